// Round 4
// baseline (1257.971 us; speedup 1.0000x reference)
//
#include <hip/hip_runtime.h>
#include <math.h>

#define NBINS 10
#define BLOCKS 768           // 3 blocks/CU (LDS-bound: 51.3 KB/block), 2 waves each
#define THREADS 128          // 2 waves/block, each wave owns a private tile
#define TILE_ROWS 64         // rows per wave-iteration
#define ROW_F4 25            // C = 100 floats = 25 float4 per row
#define TILE_F4 (TILE_ROWS * ROW_F4)   // 1600 float4 = 25.6 KB per tile
#define LPL 25               // global_load_lds per lane per tile

// ws layout: [0..29] real bins (counts/sum_conf/sum_acc), [32..61] probe scratch.
// PROBE ROUND: ece_main runs 3x -- once into ws (real), twice into ws+32
// (discarded). total - 994 = 2 x main-duration: direct measurement of the one
// number that decides whether R2 is already at the 800MB streaming roofline.

typedef const __attribute__((address_space(1))) void* gptr_t;
typedef __attribute__((address_space(3))) void* lptr_t;

__global__ void ece_zero_ws(float* ws) {
    int i = threadIdx.x;
    if (i < 64) ws[i] = 0.0f;    // zero real bins + probe scratch
}

// Identical to round-2 ece_main (best measured: 994 total).
__global__ __launch_bounds__(THREADS) void ece_main(
        const float* __restrict__ logits,
        const int* __restrict__ labels,
        float* __restrict__ ws,
        int N) {
    __shared__ __align__(16) float tile[2][TILE_ROWS * 100];  // 2 waves * 25.6 KB
    __shared__ float sbin[3 * NBINS];
    const int tid = threadIdx.x;
    if (tid < 3 * NBINS) sbin[tid] = 0.0f;
    __syncthreads();

    const int lane = tid & 63;
    const int w = tid >> 6;
    float* const mybuf = &tile[w][0];

    const long long nTiles = ((long long)N + TILE_ROWS - 1) / TILE_ROWS;
    const long long waveId = (long long)blockIdx.x * 2 + w;
    const long long nWaves = (long long)gridDim.x * 2;

    const float4* const lg4 = (const float4*)logits;
    const long long lastF4 = (long long)N * ROW_F4 - 1;

    for (long long t = waveId; t < nTiles; t += nWaves) {
        const long long base_f4 = t * (long long)TILE_F4;

        // previous iteration's ds_reads must finish before LDS is overwritten
        asm volatile("s_waitcnt lgkmcnt(0)" ::: "memory");

        #pragma unroll
        for (int j = 0; j < LPL; ++j) {
            long long g = base_f4 + j * 64 + lane;
            if (g > lastF4) g = lastF4;   // tail clamp (dest stays lane-linear)
            __builtin_amdgcn_global_load_lds(
                (gptr_t)(lg4 + g),
                (lptr_t)(mybuf + j * 256), 16, 0, 0);
        }
        asm volatile("s_waitcnt vmcnt(0)" ::: "memory");

        const long long row = t * TILE_ROWS + lane;
        if (row < (long long)N) {
            const float4* const rp = (const float4*)(mybuf + lane * 100);
            float m = -INFINITY;
            int midx = 0;
            #pragma unroll
            for (int j = 0; j < ROW_F4; ++j) {
                const float4 v = rp[j];
                const int e = 4 * j;
                if (v.x > m) { m = v.x; midx = e; }
                if (v.y > m) { m = v.y; midx = e + 1; }
                if (v.z > m) { m = v.z; midx = e + 2; }
                if (v.w > m) { m = v.w; midx = e + 3; }
            }
            const float conf = expf(m);                  // log-prob -> prob (0,1]
            const int b = (int)ceilf(conf * 10.0f) - 1;  // bin (i/10,(i+1)/10]
            const float acc = (midx == labels[row]) ? 1.0f : 0.0f;
            if (b >= 0 && b < NBINS) {
                atomicAdd(&sbin[b], 1.0f);
                atomicAdd(&sbin[NBINS + b], conf);
                atomicAdd(&sbin[2 * NBINS + b], acc);
            }
        }
    }

    __syncthreads();
    if (tid < 3 * NBINS) {
        const float s = sbin[tid];
        if (s != 0.0f) atomicAdd(&ws[tid], s);
    }
}

__global__ void ece_final(const float* __restrict__ ws, float* __restrict__ out, int N) {
    if (threadIdx.x == 0 && blockIdx.x == 0) {
        float ece = 0.0f;
        for (int b = 0; b < NBINS; ++b) {
            const float cnt = ws[b];
            if (cnt > 0.0f) {
                const float avg_conf = ws[NBINS + b] / cnt;
                const float avg_acc  = ws[2 * NBINS + b] / cnt;
                ece += fabsf(avg_conf - avg_acc) * (cnt / (float)N);
            }
        }
        out[0] = ece;
    }
}

extern "C" void kernel_launch(void* const* d_in, const int* in_sizes, int n_in,
                              void* d_out, int out_size, void* d_ws, size_t ws_size,
                              hipStream_t stream) {
    const float* logits = (const float*)d_in[0];
    const int*   labels = (const int*)d_in[1];
    float* out = (float*)d_out;
    float* ws  = (float*)d_ws;

    const int N = in_sizes[1];          // 2,000,000 rows (C = 100)

    ece_zero_ws<<<1, 64, 0, stream>>>(ws);
    ece_main<<<BLOCKS, THREADS, 0, stream>>>(logits, labels, ws, N);       // real
    ece_main<<<BLOCKS, THREADS, 0, stream>>>(logits, labels, ws + 32, N);  // probe
    ece_main<<<BLOCKS, THREADS, 0, stream>>>(logits, labels, ws + 32, N);  // probe
    ece_final<<<1, 64, 0, stream>>>(ws, out, N);
}

// Round 5
// 989.254 us; speedup vs baseline: 1.2716x; 1.2716x over previous
//
#include <hip/hip_runtime.h>
#include <math.h>

#define NBINS 10
#define BLOCKS 768           // 3 blocks/CU (LDS-bound: 51.3 KB/block), 2 waves each
#define THREADS 128          // 2 waves/block; each wave owns a private tile
#define TILE_ROWS 64         // rows per wave-iteration
#define ROW_F4 25            // C = 100 floats = 25 float4 per row
#define TILE_F4 (TILE_ROWS * ROW_F4)   // 1600 float4 = 25.6 KB per tile
#define LPL 25               // global_load_lds per lane per tile

// ws layout: [0..9] counts, [10..19] sum_conf, [20..29] sum_acc  (floats)
//
// ROOFLINE NOTE (R4 probe, measured): this kernel's main pass runs in
// ~130 µs = 816 MB @ ~6.2 TB/s = 98% of the achievable HBM ceiling
// (poison fills in the same trace hit 6.3-6.5 TB/s). The remaining ~860 µs
// of the timed region is harness re-poisoning + input restore, outside
// kernel control. Mandatory traffic = one full logits read; nothing reads less.

typedef const __attribute__((address_space(1))) void* gptr_t;
typedef __attribute__((address_space(3))) void* lptr_t;

__global__ void ece_zero_ws(float* ws) {
    int i = threadIdx.x;
    if (i < 3 * NBINS) ws[i] = 0.0f;
}

// Wave-private LDS-staged tiles:
//  - stage: 25x global_load_lds(16B) per lane -> contiguous 1KB per wave-instr,
//    every 64B line fully consumed, 25 loads in flight per wave, no VGPR
//    round-trip.
//  - compute: lane scans its own row from LDS (25x ds_read_b128, stride 400B:
//    start banks 4*lane mod 32 -> uniform 8 accesses/bank = structural min).
//  - wave-private buffer -> vmcnt(0) only, no __syncthreads in the loop.
__global__ __launch_bounds__(THREADS) void ece_main(
        const float* __restrict__ logits,
        const int* __restrict__ labels,
        float* __restrict__ ws,
        int N) {
    __shared__ __align__(16) float tile[2][TILE_ROWS * 100];  // 2 waves * 25.6 KB
    __shared__ float sbin[3 * NBINS];
    const int tid = threadIdx.x;
    if (tid < 3 * NBINS) sbin[tid] = 0.0f;
    __syncthreads();

    const int lane = tid & 63;
    const int w = tid >> 6;
    float* const mybuf = &tile[w][0];

    const long long nTiles = ((long long)N + TILE_ROWS - 1) / TILE_ROWS;
    const long long waveId = (long long)blockIdx.x * 2 + w;
    const long long nWaves = (long long)gridDim.x * 2;

    const float4* const lg4 = (const float4*)logits;
    const long long lastF4 = (long long)N * ROW_F4 - 1;

    for (long long t = waveId; t < nTiles; t += nWaves) {
        const long long base_f4 = t * (long long)TILE_F4;

        // previous iteration's ds_reads must finish before LDS is overwritten
        asm volatile("s_waitcnt lgkmcnt(0)" ::: "memory");

        #pragma unroll
        for (int j = 0; j < LPL; ++j) {
            long long g = base_f4 + j * 64 + lane;
            if (g > lastF4) g = lastF4;   // tail clamp (dest stays lane-linear)
            __builtin_amdgcn_global_load_lds(
                (gptr_t)(lg4 + g),
                (lptr_t)(mybuf + j * 256), 16, 0, 0);
        }
        asm volatile("s_waitcnt vmcnt(0)" ::: "memory");

        const long long row = t * TILE_ROWS + lane;
        if (row < (long long)N) {
            const float4* const rp = (const float4*)(mybuf + lane * 100);
            float m = -INFINITY;
            int midx = 0;
            #pragma unroll
            for (int j = 0; j < ROW_F4; ++j) {
                const float4 v = rp[j];
                const int e = 4 * j;
                if (v.x > m) { m = v.x; midx = e; }
                if (v.y > m) { m = v.y; midx = e + 1; }
                if (v.z > m) { m = v.z; midx = e + 2; }
                if (v.w > m) { m = v.w; midx = e + 3; }
            }
            const float conf = expf(m);                  // log-prob -> prob (0,1]
            const int b = (int)ceilf(conf * 10.0f) - 1;  // bin (i/10,(i+1)/10]
            const float acc = (midx == labels[row]) ? 1.0f : 0.0f;
            if (b >= 0 && b < NBINS) {
                atomicAdd(&sbin[b], 1.0f);
                atomicAdd(&sbin[NBINS + b], conf);
                atomicAdd(&sbin[2 * NBINS + b], acc);
            }
        }
    }

    __syncthreads();
    if (tid < 3 * NBINS) {
        const float s = sbin[tid];
        if (s != 0.0f) atomicAdd(&ws[tid], s);
    }
}

__global__ void ece_final(const float* __restrict__ ws, float* __restrict__ out, int N) {
    if (threadIdx.x == 0 && blockIdx.x == 0) {
        float ece = 0.0f;
        for (int b = 0; b < NBINS; ++b) {
            const float cnt = ws[b];
            if (cnt > 0.0f) {
                const float avg_conf = ws[NBINS + b] / cnt;
                const float avg_acc  = ws[2 * NBINS + b] / cnt;
                ece += fabsf(avg_conf - avg_acc) * (cnt / (float)N);
            }
        }
        out[0] = ece;
    }
}

extern "C" void kernel_launch(void* const* d_in, const int* in_sizes, int n_in,
                              void* d_out, int out_size, void* d_ws, size_t ws_size,
                              hipStream_t stream) {
    const float* logits = (const float*)d_in[0];
    const int*   labels = (const int*)d_in[1];
    float* out = (float*)d_out;
    float* ws  = (float*)d_ws;

    const int N = in_sizes[1];          // 2,000,000 rows (C = 100)

    ece_zero_ws<<<1, 64, 0, stream>>>(ws);
    ece_main<<<BLOCKS, THREADS, 0, stream>>>(logits, labels, ws, N);
    ece_final<<<1, 64, 0, stream>>>(ws, out, N);
}